// Round 1
// 51.459 us; speedup vs baseline: 1.3689x; 1.3689x over previous
//
#include <hip/hip_runtime.h>

#define BS   128
#define SEQ  64
#define DD   64
#define HH   128
#define G4   512   // 4*H
#define OUTN 4

typedef float    f32x4 __attribute__((ext_vector_type(4)));
typedef unsigned u32x4 __attribute__((ext_vector_type(4)));
typedef _Float16 f16x8 __attribute__((ext_vector_type(8)));
typedef _Float16 f16x2 __attribute__((ext_vector_type(2)));

__device__ __forceinline__ float sigm(float v) {
    // v_rcp_f32 (~1e-7 rel err) instead of IEEE divide: off the critical chain budget
    return __builtin_amdgcn_rcpf(1.0f + __expf(-v));
}

// ============================================================================
// Kernel 1: attention context (state term constant over s -> cancels in the
// seq-softmax -> ctx is step-invariant). One block per batch. r11/r16-proven.
// ============================================================================
__global__ void __launch_bounds__(256) ctx_kernel(
    const float* __restrict__ x,    // [BS, SEQ, DD]
    const float* __restrict__ Wa,   // [DD+4H, DD] (rows >= DD cancel)
    float* __restrict__ ctx_ws)     // [BS, DD]
{
    const int batch = blockIdx.x;
    const int t     = threadIdx.x;
    const int lane  = t & 63;

    __shared__ float xs[SEQ * DD];
    __shared__ float was[DD * DD];
    __shared__ float xa[SEQ * DD];
    __shared__ float pmax[4 * 64], psum[4 * 64], pctx[4 * 64];
    __shared__ float fmx[DD];

    const float* xb = x + (size_t)batch * SEQ * DD;
    for (int i = t; i < SEQ * DD; i += 256) {
        xs[i]  = xb[i];
        was[i] = Wa[i];
    }
    __syncthreads();

    {   // XA = x_b @ Wa_x, register-tiled (d = lane, 16 s-rows)
        const int d  = lane;
        const int sb = (t >> 6) * 16;
        float acc[16];
        #pragma unroll
        for (int i = 0; i < 16; ++i) acc[i] = 0.0f;
        for (int kk = 0; kk < 16; ++kk) {
            float wk0 = was[(4 * kk + 0) * DD + d];
            float wk1 = was[(4 * kk + 1) * DD + d];
            float wk2 = was[(4 * kk + 2) * DD + d];
            float wk3 = was[(4 * kk + 3) * DD + d];
            #pragma unroll
            for (int i = 0; i < 16; ++i) {
                float4 xv = *(const float4*)&xs[(sb + i) * DD + 4 * kk];
                acc[i] = fmaf(xv.x, wk0, fmaf(xv.y, wk1,
                         fmaf(xv.z, wk2, fmaf(xv.w, wk3, acc[i]))));
            }
        }
        #pragma unroll
        for (int i = 0; i < 16; ++i) xa[(sb + i) * DD + d] = acc[i];
    }
    __syncthreads();

    {   // softmax partials over s
        const int d = lane, g4 = t >> 6;
        float m = -1e30f;
        #pragma unroll
        for (int j = 0; j < 16; ++j) m = fmaxf(m, xa[(g4 * 16 + j) * DD + d]);
        pmax[g4 * 64 + d] = m;
    }
    __syncthreads();
    if (t < DD) {
        float m = -1e30f;
        #pragma unroll
        for (int g = 0; g < 4; ++g) m = fmaxf(m, pmax[g * 64 + t]);
        fmx[t] = m;
    }
    __syncthreads();
    {
        const int d = lane, g4 = t >> 6;
        const float m = fmx[d];
        float sm = 0.0f, cc = 0.0f;
        #pragma unroll
        for (int j = 0; j < 16; ++j) {
            const int s = g4 * 16 + j;
            float e = __expf(xa[s * DD + d] - m);
            sm += e;
            cc += e * xs[s * DD + d];
        }
        psum[g4 * 64 + d] = sm;
        pctx[g4 * 64 + d] = cc;
    }
    __syncthreads();
    if (t < DD) {
        float sm = 0.0f, cc = 0.0f;
        #pragma unroll
        for (int g = 0; g < 4; ++g) { sm += psum[g * 64 + t]; cc += pctx[g * 64 + t]; }
        ctx_ws[batch * DD + t] = cc / sm;
    }
}

// ============================================================================
// Kernel 2: recurrence. NEW 8-wave partition: wave w owns h-cols w*16..w*16+15;
// its 4 col-tiles ARE the 4 gates (tau = 0:i 1:f 2:g 3:o, col = tau*HH+w*16+c).
// A-row broadcast makes all C rows duplicates, so C[tau][0] IS gate tau of
// hcol w*16+c on every lane: ZERO extraction ops (old mux4 + DPP swap chain
// deleted). zc is pre-folded into the MFMA C-init. 2 waves/SIMD so one wave's
// nonlin/ds chains hide under the partner's MFMA issue. 16 MFMAs/wave/step,
// same 128 MFMAs/CU/step matrix-pipe load as before. 1 barrier/step.
// ============================================================================
__global__ void __launch_bounds__(512, 2) rec_kernel(
    const float* __restrict__ ctx_ws,   // [BS, DD]
    const float* __restrict__ Wi,  const float* __restrict__ Wh,
    const float* __restrict__ b,
    const float* __restrict__ Wvi, const float* __restrict__ Wvh,
    const float* __restrict__ bv,
    float* __restrict__ hfinal)         // [BS, 2H] f32
{
    const int batch = blockIdx.x >> 1;
    const int cell  = blockIdx.x & 1;
    const int t     = threadIdx.x;
    const int w     = t >> 6;           // wave 0..7
    const int l     = t & 63;
    const int c     = l & 15;           // B/C column lane id
    const int g     = l >> 4;           // k-group id

    const float* __restrict__ Wx   = cell ? Wvi : Wi;
    const float* __restrict__ Whh  = cell ? Wvh : Wh;
    const float* __restrict__ bias = cell ? bv  : b;

    __shared__ __align__(16) _Float16 ctxA[64];   // 1 row x 64 k (f16)
    __shared__ __align__(16) _Float16 h2[2][HH];  // dbuf h (f16)

    // stage ctx row (32 packed dwords); zero BOTH h buffers (128 dwords)
    if (t < 32) {
        f16x2 p;
        p.x = (_Float16)ctx_ws[batch * DD + 2 * t];
        p.y = (_Float16)ctx_ws[batch * DD + 2 * t + 1];
        ((unsigned*)ctxA)[t] = __builtin_bit_cast(unsigned, p);
    }
    if (t >= 64 && t < 192) ((unsigned*)h2)[t - 64] = 0u;

    const int colbase = w * 16 + c;     // my owned h column (0..127)

    __syncthreads();

    // ---- zcv[tau] = bias + ctx @ Wx for col tau*HH+colbase (rows duplicated,
    //      so zcv[tau] = {z,z,z,z} -> usable directly as MFMA C-init) ----
    f32x4 zcv[4];
    {
        f16x8 ax[2];
        #pragma unroll
        for (int ks = 0; ks < 2; ++ks)
            ax[ks] = __builtin_bit_cast(f16x8,
                *(const u32x4*)((const unsigned*)ctxA + ks * 16 + g * 4));
        #pragma unroll
        for (int tau = 0; tau < 4; ++tau) {
            float bb = bias[tau * HH + colbase];
            f32x4 acc = {bb, bb, bb, bb};
            #pragma unroll
            for (int ks = 0; ks < 2; ++ks) {
                f16x8 bx;
                #pragma unroll
                for (int q = 0; q < 8; ++q)
                    bx[q] = (_Float16)Wx[(ks * 32 + g * 8 + q) * G4 + tau * HH + colbase];
                acc = __builtin_amdgcn_mfma_f32_16x16x32_f16(ax[ks], bx, acc, 0, 0, 0);
            }
            zcv[tau] = acc;
        }
    }

    // ---- Whh B-fragments: 16 x f16x8 = 64 regs/lane, register-resident ----
    f16x8 bh[16];
    #pragma unroll
    for (int tau = 0; tau < 4; ++tau)
        #pragma unroll
        for (int ks = 0; ks < 4; ++ks) {
            f16x8 f;
            #pragma unroll
            for (int q = 0; q < 8; ++q)
                f[q] = (_Float16)Whh[(ks * 32 + g * 8 + q) * G4 + tau * HH + colbase];
            bh[tau * 4 + ks] = f;
        }

    float c_state = 0.0f, h_last = 0.0f;
    int pb = 0;

    for (int step = 0; step < SEQ; ++step) {
        // A-frags: single h row, 4 distinct 16B addrs (disjoint banks), broadcast
        const unsigned* hb = (const unsigned*)h2[pb];
        f16x8 A[4];
        #pragma unroll
        for (int ks = 0; ks < 4; ++ks)
            A[ks] = __builtin_bit_cast(f16x8, *(const u32x4*)(hb + ks * 16 + g * 4));

        // 16 MFMAs, C initialized from zc (bias + ctx@Wx pre-folded)
        f32x4 C0 = zcv[0], C1 = zcv[1], C2 = zcv[2], C3 = zcv[3];
        #pragma unroll
        for (int ks = 0; ks < 4; ++ks) {
            C0 = __builtin_amdgcn_mfma_f32_16x16x32_f16(A[ks], bh[0 * 4 + ks], C0, 0, 0, 0);
            C1 = __builtin_amdgcn_mfma_f32_16x16x32_f16(A[ks], bh[1 * 4 + ks], C1, 0, 0, 0);
            C2 = __builtin_amdgcn_mfma_f32_16x16x32_f16(A[ks], bh[2 * 4 + ks], C2, 0, 0, 0);
            C3 = __builtin_amdgcn_mfma_f32_16x16x32_f16(A[ks], bh[3 * 4 + ks], C3, 0, 0, 0);
        }

        // gates are direct MFMA outputs — no cross-lane extraction at all
        const float gi = C0[0], gf = C1[0], gg = C2[0], go = C3[0];
        const float tg = 2.0f * sigm(2.0f * gg) - 1.0f;             // tanh(g)
        c_state  = sigm(gf) * c_state + sigm(gi) * tg;
        const float hn = sigm(go) * (2.0f * sigm(2.0f * c_state) - 1.0f);
        h_last = hn;

        if (g == 0)
            h2[pb ^ 1][colbase] = (_Float16)hn;
        __syncthreads();
        pb ^= 1;
    }

    if (g == 0)
        hfinal[batch * (2 * HH) + cell * HH + colbase] = h_last;
}

// ============================================================================
// Kernel 3: out[b,o] = bfc[o] + sum_k hfinal[b,k] * Wfc[k,o]
// ============================================================================
__global__ void __launch_bounds__(512) chaotic_out(
    const float* __restrict__ hfinal,  // [BS, 2H] f32
    const float* __restrict__ Wfc,     // [2H, OUTN]
    const float* __restrict__ bfc,     // [OUTN]
    float* __restrict__ out)           // [BS, OUTN]
{
    int idx = threadIdx.x;
    if (idx >= BS * OUTN) return;
    const int bt = idx >> 2;
    const int o  = idx & 3;
    float acc = bfc[o];
    const float* hrow = hfinal + bt * (2 * HH);
    #pragma unroll 8
    for (int k = 0; k < 2 * HH; k++)
        acc = fmaf(hrow[k], Wfc[k * OUTN + o], acc);
    out[idx] = acc;
}

extern "C" void kernel_launch(void* const* d_in, const int* in_sizes, int n_in,
                              void* d_out, int out_size, void* d_ws, size_t ws_size,
                              hipStream_t stream) {
    const float* x   = (const float*)d_in[0];
    const float* Wa  = (const float*)d_in[1];
    // d_in[2] = ba : constant along softmax axis -> cancels, unused
    const float* Wi  = (const float*)d_in[3];
    const float* Wh  = (const float*)d_in[4];
    const float* b   = (const float*)d_in[5];
    const float* Wvi = (const float*)d_in[6];
    const float* Wvh = (const float*)d_in[7];
    const float* bv  = (const float*)d_in[8];
    const float* Wfc = (const float*)d_in[9];
    const float* bfc = (const float*)d_in[10];

    float* hfinal = (float*)d_ws;                              // 128 KB
    float* ctx_ws = (float*)((char*)d_ws + 128 * 1024);        // 32 KB
    float* out    = (float*)d_out;

    ctx_kernel<<<BS, 256, 0, stream>>>(x, Wa, ctx_ws);
    rec_kernel<<<BS * 2, 512, 0, stream>>>(ctx_ws, Wi, Wh, b, Wvi, Wvh, bv, hfinal);
    chaotic_out<<<1, 512, 0, stream>>>(hfinal, Wfc, bfc, out);
}